// Round 1
// baseline (659.202 us; speedup 1.0000x reference)
//
#include <hip/hip_runtime.h>
#include <stdint.h>

// Problem constants: B=8, C=256, N=2048, 2C=512, 3*2C=1536.
// Pipeline (algebraically optimized: x3@(x1^T x2) == (x3@x1^T)@x2):
//   y  = Wcat @ feat            [8,1536,2048]   (Wcat = [W1;W2;W3])
//   y  = lrelu(inorm(y))        in-place; x1=y[:, 0:512], x2=y[:,512:1024], x3=y[:,1024:1536]
//   Am = x3 @ x1^T              [8,512,512]
//   x4 = x1 - Am @ x2           [8,512,2048]
//   z  = W4 @ x4                [8,256,2048]
//   out= lrelu(inorm(z))

#define LRELU_SLOPE 0.2f
#define EPS_IN 1e-5f

constexpr int APAD = 132;  // 128 + 4: keeps 16B alignment of rows (132*4=528 % 16 == 0)

// ---------------------------------------------------------------------------
// NN GEMM, 128x128 tile, BK=16, 256 threads, 8x8 micro-tile.
// C[i,j] = (SUB ? D[i,j] - : ) sum_k A[i,k]*B[k,j]
// Grid: (N/128, M/128, batch). M,N,K divisible by 128/128/16.
// ---------------------------------------------------------------------------
template<bool SUB>
__global__ __launch_bounds__(256)
void gemm_nn128(const float* __restrict__ A, const float* __restrict__ B,
                const float* __restrict__ D, float* __restrict__ C,
                int K, int lda, int ldb, int ldd, int ldc,
                int64_t sA, int64_t sB, int64_t sD, int64_t sC)
{
    const int bz = blockIdx.z;
    A += (size_t)bz * sA;
    B += (size_t)bz * sB;
    C += (size_t)bz * sC;
    if constexpr (SUB) D += (size_t)bz * sD;

    const int i0 = blockIdx.y * 128;
    const int j0 = blockIdx.x * 128;

    __shared__ float As[16][APAD];  // transposed A tile: As[k][i]
    __shared__ float Bs[16][APAD];  // Bs[k][j]

    const int t = threadIdx.x;
    // A loader: 128 rows x 16 k = 2048 floats, 2x float4 per thread
    const int a_kq = t & 3;        // which float4 along k
    const int a_row = t >> 2;      // 0..63, second row at +64
    // B loader: 16 rows x 128 cols, 2x float4 per thread
    const int b_kk = t >> 5;       // 0..7, second row at +8
    const int b_jq = t & 31;       // float4 index along j

    // compute mapping: wave-local 8x8 arrangement -> 2-way-max LDS bank aliasing
    const int w = t >> 6, l = t & 63;
    const int r8 = ((w >> 1) << 3) + (l >> 3);  // 0..15
    const int c8 = ((w & 1) << 3) + (l & 7);    // 0..15

    float acc[8][8] = {};

    const float* Ap0 = A + (size_t)(i0 + a_row) * lda + a_kq * 4;
    const float* Ap1 = Ap0 + (size_t)64 * lda;
    const float* Bp0 = B + (size_t)b_kk * ldb + j0 + b_jq * 4;
    const float* Bp1 = Bp0 + (size_t)8 * ldb;

    for (int k0 = 0; k0 < K; k0 += 16) {
        const float4 av0 = *(const float4*)(Ap0 + k0);
        const float4 av1 = *(const float4*)(Ap1 + k0);
        const float4 bv0 = *(const float4*)(Bp0 + (size_t)k0 * ldb);
        const float4 bv1 = *(const float4*)(Bp1 + (size_t)k0 * ldb);
        __syncthreads();  // previous iteration's LDS reads must finish
        As[a_kq * 4 + 0][a_row] = av0.x;
        As[a_kq * 4 + 1][a_row] = av0.y;
        As[a_kq * 4 + 2][a_row] = av0.z;
        As[a_kq * 4 + 3][a_row] = av0.w;
        As[a_kq * 4 + 0][a_row + 64] = av1.x;
        As[a_kq * 4 + 1][a_row + 64] = av1.y;
        As[a_kq * 4 + 2][a_row + 64] = av1.z;
        As[a_kq * 4 + 3][a_row + 64] = av1.w;
        *(float4*)&Bs[b_kk][b_jq * 4] = bv0;
        *(float4*)&Bs[b_kk + 8][b_jq * 4] = bv1;
        __syncthreads();
#pragma unroll
        for (int kk = 0; kk < 16; ++kk) {
            float a0[8], b0[8];
            *(float4*)&a0[0] = *(const float4*)&As[kk][r8 * 8];
            *(float4*)&a0[4] = *(const float4*)&As[kk][r8 * 8 + 4];
            *(float4*)&b0[0] = *(const float4*)&Bs[kk][c8 * 8];
            *(float4*)&b0[4] = *(const float4*)&Bs[kk][c8 * 8 + 4];
#pragma unroll
            for (int u = 0; u < 8; ++u)
#pragma unroll
                for (int v = 0; v < 8; ++v)
                    acc[u][v] += a0[u] * b0[v];
        }
    }

#pragma unroll
    for (int u = 0; u < 8; ++u) {
        const int i = i0 + r8 * 8 + u;
        float4 o0 = make_float4(acc[u][0], acc[u][1], acc[u][2], acc[u][3]);
        float4 o1 = make_float4(acc[u][4], acc[u][5], acc[u][6], acc[u][7]);
        if constexpr (SUB) {
            const float4 d0 = *(const float4*)&D[(size_t)i * ldd + j0 + c8 * 8];
            const float4 d1 = *(const float4*)&D[(size_t)i * ldd + j0 + c8 * 8 + 4];
            o0.x = d0.x - o0.x; o0.y = d0.y - o0.y; o0.z = d0.z - o0.z; o0.w = d0.w - o0.w;
            o1.x = d1.x - o1.x; o1.y = d1.y - o1.y; o1.z = d1.z - o1.z; o1.w = d1.w - o1.w;
        }
        *(float4*)&C[(size_t)i * ldc + j0 + c8 * 8] = o0;
        *(float4*)&C[(size_t)i * ldc + j0 + c8 * 8 + 4] = o1;
    }
}

// ---------------------------------------------------------------------------
// NT GEMM, 64x64 tile, BK=16, 64 threads (1 wave), 8x8 micro-tile.
// C[i,j] = sum_k A[i,k] * Bm[j,k]   (both operands k-contiguous)
// Grid: (N/64, M/64, batch)
// ---------------------------------------------------------------------------
__global__ __launch_bounds__(64)
void gemm_nt64(const float* __restrict__ A, const float* __restrict__ Bm,
               float* __restrict__ C,
               int K, int lda, int ldb, int ldc,
               int64_t sA, int64_t sB, int64_t sC)
{
    const int bz = blockIdx.z;
    A  += (size_t)bz * sA;
    Bm += (size_t)bz * sB;
    C  += (size_t)bz * sC;

    const int i0 = blockIdx.y * 64;
    const int j0 = blockIdx.x * 64;

    __shared__ float As[16][68];  // 68*4=272 bytes/row, 16B-aligned
    __shared__ float Bs[16][68];

    const int l = threadIdx.x;
    const int fq = l & 3;    // float4 index along k
    const int rg = l >> 2;   // row within group of 16
    const int r8 = l >> 3, c8 = l & 7;

    float acc[8][8] = {};

    for (int k0 = 0; k0 < K; k0 += 16) {
        float4 av[4], bv[4];
#pragma unroll
        for (int q = 0; q < 4; ++q) {
            const int row = q * 16 + rg;
            av[q] = *(const float4*)&A [(size_t)(i0 + row) * lda + k0 + fq * 4];
            bv[q] = *(const float4*)&Bm[(size_t)(j0 + row) * ldb + k0 + fq * 4];
        }
        __syncthreads();
#pragma unroll
        for (int q = 0; q < 4; ++q) {
            const int row = q * 16 + rg;
            As[fq * 4 + 0][row] = av[q].x;
            As[fq * 4 + 1][row] = av[q].y;
            As[fq * 4 + 2][row] = av[q].z;
            As[fq * 4 + 3][row] = av[q].w;
            Bs[fq * 4 + 0][row] = bv[q].x;
            Bs[fq * 4 + 1][row] = bv[q].y;
            Bs[fq * 4 + 2][row] = bv[q].z;
            Bs[fq * 4 + 3][row] = bv[q].w;
        }
        __syncthreads();
#pragma unroll
        for (int kk = 0; kk < 16; ++kk) {
            float a0[8], b0[8];
            *(float4*)&a0[0] = *(const float4*)&As[kk][r8 * 8];
            *(float4*)&a0[4] = *(const float4*)&As[kk][r8 * 8 + 4];
            *(float4*)&b0[0] = *(const float4*)&Bs[kk][c8 * 8];
            *(float4*)&b0[4] = *(const float4*)&Bs[kk][c8 * 8 + 4];
#pragma unroll
            for (int u = 0; u < 8; ++u)
#pragma unroll
                for (int v = 0; v < 8; ++v)
                    acc[u][v] += a0[u] * b0[v];
        }
    }

#pragma unroll
    for (int u = 0; u < 8; ++u) {
        const int i = i0 + r8 * 8 + u;
        float4 o0 = make_float4(acc[u][0], acc[u][1], acc[u][2], acc[u][3]);
        float4 o1 = make_float4(acc[u][4], acc[u][5], acc[u][6], acc[u][7]);
        *(float4*)&C[(size_t)i * ldc + j0 + c8 * 8] = o0;
        *(float4*)&C[(size_t)i * ldc + j0 + c8 * 8 + 4] = o1;
    }
}

// ---------------------------------------------------------------------------
// Fused per-row instance-norm + leaky-relu. One block per row of 2048 floats.
// Single global read + single global write (row lives in registers).
// ---------------------------------------------------------------------------
__global__ __launch_bounds__(256)
void row_norm_lrelu(const float* __restrict__ in, float* __restrict__ out)
{
    const size_t row = blockIdx.x;
    const float4* p = (const float4*)(in + row * 2048);
    float4* q = (float4*)(out + row * 2048);
    const int t = threadIdx.x;

    float4 v0 = p[t];
    float4 v1 = p[t + 256];

    float s  = v0.x + v0.y + v0.z + v0.w + v1.x + v1.y + v1.z + v1.w;
    float ss = v0.x * v0.x + v0.y * v0.y + v0.z * v0.z + v0.w * v0.w +
               v1.x * v1.x + v1.y * v1.y + v1.z * v1.z + v1.w * v1.w;

#pragma unroll
    for (int off = 32; off > 0; off >>= 1) {
        s  += __shfl_down(s, off, 64);
        ss += __shfl_down(ss, off, 64);
    }

    __shared__ float red[10];
    const int wid = t >> 6;
    if ((t & 63) == 0) { red[wid] = s; red[4 + wid] = ss; }
    __syncthreads();
    if (t == 0) {
        const float S  = red[0] + red[1] + red[2] + red[3];
        const float SS = red[4] + red[5] + red[6] + red[7];
        const float mu = S * (1.0f / 2048.0f);
        const float var = SS * (1.0f / 2048.0f) - mu * mu;
        red[8] = mu;
        red[9] = rsqrtf(var + EPS_IN);
    }
    __syncthreads();
    const float mu = red[8], rs = red[9];

#define NRM(x) { float e = ((x) - mu) * rs; (x) = (e >= 0.0f) ? e : LRELU_SLOPE * e; }
    NRM(v0.x) NRM(v0.y) NRM(v0.z) NRM(v0.w)
    NRM(v1.x) NRM(v1.y) NRM(v1.z) NRM(v1.w)
#undef NRM

    q[t] = v0;
    q[t + 256] = v1;
}

// ---------------------------------------------------------------------------
extern "C" void kernel_launch(void* const* d_in, const int* in_sizes, int n_in,
                              void* d_out, int out_size, void* d_ws, size_t ws_size,
                              hipStream_t stream)
{
    const float* feat = (const float*)d_in[0];  // [8,256,2048]
    const float* W1   = (const float*)d_in[1];  // [512,256]
    const float* W2   = (const float*)d_in[2];
    const float* W3   = (const float*)d_in[3];
    const float* W4   = (const float*)d_in[4];  // [256,512]
    float* out = (float*)d_out;                 // [8,256,2048]
    float* ws  = (float*)d_ws;

    // workspace layout (floats)
    float* y    = ws;                 // [8][1536][2048] = 25165824
    float* Am   = ws + 25165824;      // [8][512][512]   =  2097152
    float* x4   = ws + 27262976;      // [8][512][2048]  =  8388608
    float* Wc   = ws + 35651584;      // [1536][256]     =   393216
    float* z    = y;                  // reuse y (dead after x4 is built)

    const size_t Wbytes = (size_t)512 * 256 * sizeof(float);
    hipMemcpyAsync(Wc,          W1, Wbytes, hipMemcpyDeviceToDevice, stream);
    hipMemcpyAsync(Wc + 131072, W2, Wbytes, hipMemcpyDeviceToDevice, stream);
    hipMemcpyAsync(Wc + 262144, W3, Wbytes, hipMemcpyDeviceToDevice, stream);

    // 1) y = Wcat @ feat   (M=1536, N=2048, K=256)
    gemm_nn128<false><<<dim3(16, 12, 8), 256, 0, stream>>>(
        Wc, feat, nullptr, y,
        /*K*/256, /*lda*/256, /*ldb*/2048, /*ldd*/0, /*ldc*/2048,
        /*sA*/0, /*sB*/524288, /*sD*/0, /*sC*/3145728);

    // 2) y = lrelu(inorm(y)) in place (8*1536 rows)
    row_norm_lrelu<<<12288, 256, 0, stream>>>(y, y);

    // 3) Am = x3 @ x1^T   (M=512, N=512, K=2048)
    gemm_nt64<<<dim3(8, 8, 8), 64, 0, stream>>>(
        y + 2097152 /*x3*/, y /*x1*/, Am,
        /*K*/2048, /*lda*/2048, /*ldb*/2048, /*ldc*/512,
        /*sA*/3145728, /*sB*/3145728, /*sC*/262144);

    // 4) x4 = x1 - Am @ x2   (M=512, N=2048, K=512)
    gemm_nn128<true><<<dim3(16, 4, 8), 256, 0, stream>>>(
        Am, y + 1048576 /*x2*/, y /*x1 (D)*/, x4,
        /*K*/512, /*lda*/512, /*ldb*/2048, /*ldd*/2048, /*ldc*/2048,
        /*sA*/262144, /*sB*/3145728, /*sD*/3145728, /*sC*/1048576);

    // 5) z = W4 @ x4   (M=256, N=2048, K=512)
    gemm_nn128<false><<<dim3(16, 2, 8), 256, 0, stream>>>(
        W4, x4, nullptr, z,
        /*K*/512, /*lda*/512, /*ldb*/2048, /*ldd*/0, /*ldc*/2048,
        /*sA*/0, /*sB*/1048576, /*sD*/0, /*sC*/524288);

    // 6) out = lrelu(inorm(z)) (8*256 rows)
    row_norm_lrelu<<<2048, 256, 0, stream>>>(z, out);
}

// Round 4
// 221.771 us; speedup vs baseline: 2.9724x; 2.9724x over previous
//
#include <hip/hip_runtime.h>
#include <stdint.h>

// B=8, C=256, N=2048. Pipeline (reassociated: x3@(x1^T x2) == (x3@x1^T)@x2):
//   Wcatb = bf16([W1;W2;W3]); W4cat = bf16([W4 | W4])  [256][1024]
//   featT = bf16(feat^T)                      [8,2048,256]
//   ybf   = Wcat @ feat  (bf16 out)           [8,1536,2048]
//   ybf   = lrelu(inorm(ybf)) in place        x1|x2|x3 slices of 512 rows
//   x2T   = x2^T (bf16)                       [8,2048,512]
//   Amb   = x3 @ x1^T (bf16)                  [8,512,512]
//   x4Ts  = split((x1 - Am @ x2)^T)           [8,2048,1024] bf16 hi|lo
//           (x4 has ~34k common-mode vs ~3k signal: single bf16 = 5-bit SNR,
//            hi+lo split restores ~16-bit mantissa)
//   z     = [W4|W4] @ [hi;lo] = W4 @ x4 (fp32) [8,256,2048]
//   out   = lrelu(inorm(z))
// All GEMMs: TN form C[m,n] = sum_k A[m,k]*B[n,k], both operands K-major,
// staged via global_load_lds(16B), 16x16x32 bf16 MFMA, 4 waves, m97 structure.

#define LRELU_SLOPE 0.2f
#define EPS_IN 1e-5f

typedef __attribute__((ext_vector_type(8))) short short8v;  // 8 bf16 (4 VGPR)
typedef __attribute__((ext_vector_type(4))) float f32x4;

__device__ __forceinline__ unsigned short f2bf(float f) {
    unsigned int u = __builtin_bit_cast(unsigned int, f);
    u = (u + 0x7fffu + ((u >> 16) & 1u)) >> 16;  // RNE
    return (unsigned short)u;
}
__device__ __forceinline__ float bf2f(unsigned short h) {
    return __builtin_bit_cast(float, (unsigned int)h << 16);
}

typedef const __attribute__((address_space(1))) unsigned int* as1_uint_ptr;
typedef __attribute__((address_space(3))) unsigned int* as3_uint_ptr;

#define GLL16(g, l) __builtin_amdgcn_global_load_lds( \
    (as1_uint_ptr)(const void*)(g), (as3_uint_ptr)(void*)(l), 16, 0, 0)

enum { EP_F32 = 0, EP_BF16 = 1, EP_SUB_T_SPLIT = 2 };

// ---------------------------------------------------------------------------
// TN bf16 MFMA GEMM. A:[M][K] k-major, B:[N][K] k-major (both bf16).
// EP_F32:  C fp32 [M][N].  EP_BF16: C bf16 [M][N].
// EP_SUB_T_SPLIT: s = D[m][n] - acc; C bf16 [N][ldc] with hi at [n][m],
//                 lo = bf16(s - hi) at [n][m + ldc/2]  (split precision).
// Grid: (N/BN, M/BM, batch). 256 threads = 4 waves (2x2).
// ---------------------------------------------------------------------------
template<int BM, int BN, int EP>
__global__ __launch_bounds__(256)
void gemm_tn(const unsigned short* __restrict__ A, const unsigned short* __restrict__ B,
             const unsigned short* __restrict__ Dm, void* __restrict__ Cv,
             int K, int lda, int ldb, int ldd, int ldc,
             int64_t sA, int64_t sB, int64_t sD, int64_t sC)
{
    constexpr int FM = BM / 32, FN = BN / 32;  // 16x16 frags per wave
    const int bz = blockIdx.z;
    A += sA * bz;
    B += sB * bz;

    const int i0 = blockIdx.y * BM;
    const int j0 = blockIdx.x * BN;

    __shared__ __align__(16) unsigned short As[BM * 32];
    __shared__ __align__(16) unsigned short Bs[BN * 32];

    const int t = threadIdx.x;
    const int w = t >> 6, l = t & 63;
    const int wr = w >> 1, wc = w & 1;

    f32x4 acc[FM][FN];
#pragma unroll
    for (int fm = 0; fm < FM; ++fm)
#pragma unroll
        for (int fn = 0; fn < FN; ++fn)
            acc[fm][fn] = (f32x4){0.f, 0.f, 0.f, 0.f};

    for (int k0 = 0; k0 < K; k0 += 32) {
        __syncthreads();  // prior iteration's LDS reads done
#pragma unroll
        for (int q = 0; q < BM / 64; ++q) {
            const int seg = w * (BM / 64) + q;              // 1KB segment
            const int row = seg * 16 + (l >> 2);
            const unsigned short* g = A + (size_t)(i0 + row) * lda + k0 + (l & 3) * 8;
            GLL16(g, &As[seg * 512]);
        }
#pragma unroll
        for (int q = 0; q < BN / 64; ++q) {
            const int seg = w * (BN / 64) + q;
            const int row = seg * 16 + (l >> 2);
            const unsigned short* g = B + (size_t)(j0 + row) * ldb + k0 + (l & 3) * 8;
            GLL16(g, &Bs[seg * 512]);
        }
        asm volatile("s_waitcnt vmcnt(0)" ::: "memory");
        __syncthreads();

        short8v a[FM], b[FN];
#pragma unroll
        for (int fm = 0; fm < FM; ++fm)
            a[fm] = *(const short8v*)&As[(wr * (BM / 2) + fm * 16 + (l & 15)) * 32 + (l >> 4) * 8];
#pragma unroll
        for (int fn = 0; fn < FN; ++fn)
            b[fn] = *(const short8v*)&Bs[(wc * (BN / 2) + fn * 16 + (l & 15)) * 32 + (l >> 4) * 8];
#pragma unroll
        for (int fm = 0; fm < FM; ++fm)
#pragma unroll
            for (int fn = 0; fn < FN; ++fn)
                acc[fm][fn] = __builtin_amdgcn_mfma_f32_16x16x32_bf16(a[fm], b[fn], acc[fm][fn], 0, 0, 0);
    }

    // Epilogue. D-frag: col = lane&15, row = (lane>>4)*4 + reg.
    const int cr4 = (l >> 4) * 4;
    const int cc = l & 15;
#pragma unroll
    for (int fm = 0; fm < FM; ++fm) {
#pragma unroll
        for (int fn = 0; fn < FN; ++fn) {
            const int grow0 = i0 + wr * (BM / 2) + fm * 16 + cr4;
            const int gcol  = j0 + wc * (BN / 2) + fn * 16 + cc;
            if constexpr (EP == EP_F32) {
                float* C = (float*)Cv + sC * bz;
#pragma unroll
                for (int r = 0; r < 4; ++r)
                    C[(size_t)(grow0 + r) * ldc + gcol] = acc[fm][fn][r];
            } else if constexpr (EP == EP_BF16) {
                unsigned short* C = (unsigned short*)Cv + sC * bz;
#pragma unroll
                for (int r = 0; r < 4; ++r)
                    C[(size_t)(grow0 + r) * ldc + gcol] = f2bf(acc[fm][fn][r]);
            } else {  // EP_SUB_T_SPLIT
                const unsigned short* D = Dm + sD * bz;
                unsigned short* C = (unsigned short*)Cv + sC * bz;
                ushort4 hi4, lo4;
#pragma unroll
                for (int r = 0; r < 4; ++r) {
                    const float s = bf2f(D[(size_t)(grow0 + r) * ldd + gcol]) - acc[fm][fn][r];
                    const unsigned short h = f2bf(s);
                    const unsigned short lo = f2bf(s - bf2f(h));
                    ((unsigned short*)&hi4)[r] = h;
                    ((unsigned short*)&lo4)[r] = lo;
                }
                *(ushort4*)&C[(size_t)gcol * ldc + grow0] = hi4;
                *(ushort4*)&C[(size_t)gcol * ldc + (ldc >> 1) + grow0] = lo4;
            }
        }
    }
}

// ---------------------------------------------------------------------------
// In-place row instance-norm + leaky-relu on bf16 rows of 2048. 1 block/row.
// ---------------------------------------------------------------------------
__global__ __launch_bounds__(256)
void row_norm_lrelu_bf16(unsigned short* __restrict__ y)
{
    const size_t row = blockIdx.x;
    uint4* p = (uint4*)(y + row * 2048);
    const int t = threadIdx.x;
    uint4 v = p[t];

    unsigned int wd[4] = {v.x, v.y, v.z, v.w};
    float f[8];
#pragma unroll
    for (int i = 0; i < 4; ++i) {
        f[2 * i]     = __builtin_bit_cast(float, wd[i] << 16);
        f[2 * i + 1] = __builtin_bit_cast(float, wd[i] & 0xffff0000u);
    }
    float s = 0.f, ss = 0.f;
#pragma unroll
    for (int i = 0; i < 8; ++i) { s += f[i]; ss += f[i] * f[i]; }

#pragma unroll
    for (int off = 32; off > 0; off >>= 1) {
        s  += __shfl_down(s, off, 64);
        ss += __shfl_down(ss, off, 64);
    }
    __shared__ float red[10];
    const int wid = t >> 6;
    if ((t & 63) == 0) { red[wid] = s; red[4 + wid] = ss; }
    __syncthreads();
    if (t == 0) {
        const float S  = red[0] + red[1] + red[2] + red[3];
        const float SS = red[4] + red[5] + red[6] + red[7];
        const float mu = S * (1.0f / 2048.0f);
        const float var = SS * (1.0f / 2048.0f) - mu * mu;
        red[8] = mu;
        red[9] = rsqrtf(var + EPS_IN);
    }
    __syncthreads();
    const float mu = red[8], rs = red[9];
#pragma unroll
    for (int i = 0; i < 8; ++i) {
        float e = (f[i] - mu) * rs;
        f[i] = (e >= 0.f) ? e : LRELU_SLOPE * e;
    }
#pragma unroll
    for (int i = 0; i < 4; ++i)
        wd[i] = (unsigned int)f2bf(f[2 * i]) | ((unsigned int)f2bf(f[2 * i + 1]) << 16);
    p[t] = make_uint4(wd[0], wd[1], wd[2], wd[3]);
}

// ---------------------------------------------------------------------------
// Row instance-norm + leaky-relu, fp32 in -> fp32 out. 1 block per 2048-row.
// ---------------------------------------------------------------------------
__global__ __launch_bounds__(256)
void row_norm_lrelu(const float* __restrict__ in, float* __restrict__ out)
{
    const size_t row = blockIdx.x;
    const float4* p = (const float4*)(in + row * 2048);
    float4* q = (float4*)(out + row * 2048);
    const int t = threadIdx.x;

    float4 v0 = p[t];
    float4 v1 = p[t + 256];

    float s  = v0.x + v0.y + v0.z + v0.w + v1.x + v1.y + v1.z + v1.w;
    float ss = v0.x * v0.x + v0.y * v0.y + v0.z * v0.z + v0.w * v0.w +
               v1.x * v1.x + v1.y * v1.y + v1.z * v1.z + v1.w * v1.w;
#pragma unroll
    for (int off = 32; off > 0; off >>= 1) {
        s  += __shfl_down(s, off, 64);
        ss += __shfl_down(ss, off, 64);
    }
    __shared__ float red[10];
    const int wid = t >> 6;
    if ((t & 63) == 0) { red[wid] = s; red[4 + wid] = ss; }
    __syncthreads();
    if (t == 0) {
        const float S  = red[0] + red[1] + red[2] + red[3];
        const float SS = red[4] + red[5] + red[6] + red[7];
        const float mu = S * (1.0f / 2048.0f);
        const float var = SS * (1.0f / 2048.0f) - mu * mu;
        red[8] = mu;
        red[9] = rsqrtf(var + EPS_IN);
    }
    __syncthreads();
    const float mu = red[8], rs = red[9];
#define NRM(x) { float e = ((x) - mu) * rs; (x) = (e >= 0.0f) ? e : LRELU_SLOPE * e; }
    NRM(v0.x) NRM(v0.y) NRM(v0.z) NRM(v0.w)
    NRM(v1.x) NRM(v1.y) NRM(v1.z) NRM(v1.w)
#undef NRM
    q[t] = v0;
    q[t + 256] = v1;
}

// ---------------------------------------------------------------------------
// 64x64-tile transpose with cast to bf16. in [R][inCols] -> out [inCols][R].
// Grid: (inCols/64, R/64, batch). 256 threads. Loads ALL 64 rows (4 passes).
// ---------------------------------------------------------------------------
template<bool F32IN>
__global__ __launch_bounds__(256)
void transpose_cast(const void* __restrict__ in, unsigned short* __restrict__ out,
                    int inCols, int outCols, int64_t sIn, int64_t sOut)
{
    __shared__ __align__(16) unsigned short tile[64][68];
    const int t = threadIdx.x;
    const int r0 = blockIdx.y * 64, c0 = blockIdx.x * 64;
    const int ir = t >> 4, ic = (t & 15) * 4;  // 16 rows x 64 cols per pass

#pragma unroll
    for (int q = 0; q < 4; ++q) {
        const int rr = q * 16 + ir;
        if constexpr (F32IN) {
            const float* ip = (const float*)in + sIn * blockIdx.z + (size_t)(r0 + rr) * inCols + c0 + ic;
            float4 v = *(const float4*)ip;
            tile[rr][ic + 0] = f2bf(v.x);
            tile[rr][ic + 1] = f2bf(v.y);
            tile[rr][ic + 2] = f2bf(v.z);
            tile[rr][ic + 3] = f2bf(v.w);
        } else {
            const unsigned short* ip = (const unsigned short*)in + sIn * blockIdx.z + (size_t)(r0 + rr) * inCols + c0 + ic;
            ushort4 v = *(const ushort4*)ip;
            tile[rr][ic + 0] = v.x;
            tile[rr][ic + 1] = v.y;
            tile[rr][ic + 2] = v.z;
            tile[rr][ic + 3] = v.w;
        }
    }
    __syncthreads();

    const int n = t & 63, kc = (t >> 6) * 16;
    unsigned short* op = out + sOut * blockIdx.z + (size_t)(c0 + n) * outCols + r0 + kc;
    unsigned int wo[8];
#pragma unroll
    for (int i = 0; i < 8; ++i)
        wo[i] = (unsigned int)tile[kc + 2 * i][n] | ((unsigned int)tile[kc + 2 * i + 1][n] << 16);
    *(uint4*)op       = make_uint4(wo[0], wo[1], wo[2], wo[3]);
    *(uint4*)(op + 8) = make_uint4(wo[4], wo[5], wo[6], wo[7]);
}

// ---------------------------------------------------------------------------
// Cast W1|W2|W3 -> Wcat bf16 [1536][256]; W4 -> W4cat bf16 [256][1024] = [W4|W4].
// ---------------------------------------------------------------------------
__global__ __launch_bounds__(256)
void cast_weights(const float* __restrict__ W1, const float* __restrict__ W2,
                  const float* __restrict__ W3, const float* __restrict__ W4,
                  unsigned short* __restrict__ Wcatb, unsigned short* __restrict__ W4cat)
{
    const int wsel = blockIdx.x >> 7;  // 0..3 (uniform per block)
    const int local = ((blockIdx.x & 127) * 256 + threadIdx.x) * 4;
    const float* src = (wsel == 0) ? W1 : (wsel == 1) ? W2 : (wsel == 2) ? W3 : W4;
    float4 v = *(const float4*)(src + local);
    ushort4 pk = make_ushort4(f2bf(v.x), f2bf(v.y), f2bf(v.z), f2bf(v.w));
    if (wsel < 3) {
        *(ushort4*)(Wcatb + (size_t)wsel * 131072 + local) = pk;
    } else {
        const int o = local >> 9, c = local & 511;  // W4 is [256][512]
        *(ushort4*)(W4cat + (size_t)o * 1024 + c)       = pk;
        *(ushort4*)(W4cat + (size_t)o * 1024 + 512 + c) = pk;
    }
}

// ---------------------------------------------------------------------------
extern "C" void kernel_launch(void* const* d_in, const int* in_sizes, int n_in,
                              void* d_out, int out_size, void* d_ws, size_t ws_size,
                              hipStream_t stream)
{
    const float* feat = (const float*)d_in[0];  // [8,256,2048]
    const float* W1   = (const float*)d_in[1];  // [512,256]
    const float* W2   = (const float*)d_in[2];
    const float* W3   = (const float*)d_in[3];
    const float* W4   = (const float*)d_in[4];  // [256,512]
    float* out = (float*)d_out;                 // [8,256,2048]

    char* w = (char*)d_ws;
    unsigned short* ybf   = (unsigned short*)(w + 0);          // 50331648 B
    unsigned short* featT = (unsigned short*)(w + 50331648);   //  8388608 B
    unsigned short* x2T   = (unsigned short*)(w + 58720256);   // 16777216 B
    unsigned short* Amb   = (unsigned short*)(w + 75497472);   //  4194304 B
    unsigned short* x4Ts  = (unsigned short*)(w + 79691776);   // 33554432 B (hi|lo)
    float*          z     = (float*)(w + 113246208);           // 16777216 B
    unsigned short* Wcatb = (unsigned short*)(w + 130023424);  //   786432 B
    unsigned short* W4cat = (unsigned short*)(w + 130809856);  //   524288 B

    cast_weights<<<512, 256, 0, stream>>>(W1, W2, W3, W4, Wcatb, W4cat);

    // featT[b] = bf16(feat[b]^T)  [2048][256]
    transpose_cast<true><<<dim3(32, 4, 8), 256, 0, stream>>>(
        feat, featT, 2048, 256, 524288, 524288);

    // ybf = Wcat @ feat : M=1536 N=2048 K=256 (A shared, B=featT)
    gemm_tn<128, 128, EP_BF16><<<dim3(16, 12, 8), 256, 0, stream>>>(
        Wcatb, featT, nullptr, ybf,
        /*K*/256, /*lda*/256, /*ldb*/256, /*ldd*/0, /*ldc*/2048,
        /*sA*/0, /*sB*/524288, /*sD*/0, /*sC*/3145728);

    // in-place norm+lrelu over all 8*1536 rows
    row_norm_lrelu_bf16<<<12288, 256, 0, stream>>>(ybf);

    // x2T[b] = x2[b]^T  [2048][512]
    transpose_cast<false><<<dim3(32, 8, 8), 256, 0, stream>>>(
        ybf + 1048576, x2T, 2048, 512, 3145728, 1048576);

    // Amb = x3 @ x1^T : M=512 N=512 K=2048
    gemm_tn<64, 64, EP_BF16><<<dim3(8, 8, 8), 256, 0, stream>>>(
        ybf + 2097152, ybf, nullptr, Amb,
        /*K*/2048, /*lda*/2048, /*ldb*/2048, /*ldd*/0, /*ldc*/512,
        /*sA*/3145728, /*sB*/3145728, /*sD*/0, /*sC*/262144);

    // x4Ts = split((x1 - Am @ x2)^T) : M=512 N=2048 K=512, D=x1
    gemm_tn<128, 128, EP_SUB_T_SPLIT><<<dim3(16, 4, 8), 256, 0, stream>>>(
        Amb, x2T, ybf, x4Ts,
        /*K*/512, /*lda*/512, /*ldb*/512, /*ldd*/2048, /*ldc(hi|lo)*/1024,
        /*sA*/262144, /*sB*/1048576, /*sD*/3145728, /*sC*/2097152);

    // z = [W4|W4] @ [hi;lo] : M=256 N=2048 K=1024, fp32 out
    gemm_tn<128, 128, EP_F32><<<dim3(16, 2, 8), 256, 0, stream>>>(
        W4cat, x4Ts, nullptr, z,
        /*K*/1024, /*lda*/1024, /*ldb*/1024, /*ldd*/0, /*ldc*/2048,
        /*sA*/0, /*sB*/2097152, /*sD*/0, /*sC*/524288);

    // out = lrelu(inorm(z))
    row_norm_lrelu<<<2048, 256, 0, stream>>>(z, out);
}